// Round 8
// baseline (7344.991 us; speedup 1.0000x reference)
//
#include <hip/hip_runtime.h>
#include <math.h>

#define T_  512
#define B_  128
#define H_  256
#define A_  18
#define G4H 1024
#define TB_ (T_*B_)

// d_out layout (floats): [logits T*B*A][baseline T*B][action T*B][hT 2*B*H][cT 2*B*H]
#define OUT_BASE  (TB_*A_)
#define OUT_ACT   (OUT_BASE + TB_)
#define OUT_HT    (OUT_ACT + TB_)
#define OUT_CT    (OUT_HT + 2*B_*H_)

// workspace (floats): double-buffered h per layer (parity = t&1), private c per layer,
// then 256 uint phase-stamp cells (one per WG, memset once per replay)
#define WS_H0  0
#define WS_H1  (2*B_*H_)
#define WS_C0  (4*B_*H_)
#define WS_C1  (5*B_*H_)
#define WS_CTR (6*B_*H_)

// SINGLE-DISPATCH PERSISTENT PIPELINE, v8.
// v7 post-mortem: phase body is DS-pipe + serial-chain bound. Changes:
// (1) 16-lane reduce via DPP row_ror adds (VALU) instead of ds_swizzle shuffles;
// (2) gate-major row remap: wave w owns rows ri in {2w,2w+1} for ALL 4 gates ->
//     after reduce each wave holds complete i,f,g,o for its (hi,batch) set ->
//     per-wave cell update with NO gates LDS and NO mid-phase barrier; swaps
//     issue early and their ack overlaps other waves' FMA;
// (3) head duty moved to L0 WGs (balances L1's double staging; h1(p-2) is
//     same-cluster, 1-phase slack);
// (4) L1's two sc staging load sets issue back-to-back (one latency).
// Sync skeleton is v6/v7's proven one: cross-WG data writes = returning atomic
// swaps (acked at the coherence point by vmcnt(0)), store-stamp arrival,
// 32-lane poll of the 32-WG dependency-closed cluster, no cache-maintenance.

__device__ __forceinline__ float cload(const float* p) {
    return __hip_atomic_load((float*)p, __ATOMIC_RELAXED, __HIP_MEMORY_SCOPE_SYSTEM);
}
__device__ __forceinline__ float4 cload4(const float* p) {   // 16B-aligned
    union { unsigned long long u[2]; float4 f; } r;
    r.u[0] = __hip_atomic_load((const unsigned long long*)p,
                               __ATOMIC_RELAXED, __HIP_MEMORY_SCOPE_SYSTEM);
    r.u[1] = __hip_atomic_load((const unsigned long long*)(p + 2),
                               __ATOMIC_RELAXED, __HIP_MEMORY_SCOPE_SYSTEM);
    return r.f;
}
// ordered data write: atomic exchange, returning form forced by asm sink
__device__ __forceinline__ void cswap(float* p, float v) {
    float old = __hip_atomic_exchange(p, v, __ATOMIC_RELAXED, __HIP_MEMORY_SCOPE_SYSTEM);
    asm volatile("" :: "v"(old));
}
// DPP row_ror (within 16-lane rows); 4 rotation-adds = full 16-lane sum on VALU
template<int N>
__device__ __forceinline__ float ror16(float v) {
    return __int_as_float(__builtin_amdgcn_update_dpp(
        0, __float_as_int(v), 0x120 | N, 0xF, 0xF, true));
}
__device__ __forceinline__ float rowsum16(float v) {
    v += ror16<8>(v); v += ror16<4>(v); v += ror16<2>(v); v += ror16<1>(v);
    return v;   // every lane in the 16-row holds the total
}

__global__ __launch_bounds__(512, 1) void lstm_persist(
    const float* __restrict__ x, const int* __restrict__ done,
    const float* __restrict__ h0in, const float* __restrict__ c0in,
    const float* __restrict__ w_ih, const float* __restrict__ w_hh,
    const float* __restrict__ b_ih, const float* __restrict__ b_hh,
    const float* __restrict__ Wp, const float* __restrict__ bp,
    const float* __restrict__ Wb, const float* __restrict__ bb,
    float* __restrict__ out, float* __restrict__ ws)
{
    __shared__ __align__(16) float wlds[64*2*H_];      // 128 KB weight slice
    __shared__ __align__(16) float stg[16*H_];         // 16 KB activation stage
    __shared__ float hlog[19];
    // total ~144.1 KB < 160 KB; 1 WG/CU

    const int wg   = blockIdx.x;
    const int tid  = threadIdx.x;
    const int l    = wg >> 7;            // 0: layer0 (+head duty), 1: layer1
    const int wl   = wg & 127;
    const int lane = tid & 63;
    const int w    = tid >> 6;           // wave 0..7
    const int kc   = lane & 15;          // K-chunk owner (16 floats, k = q*64+kc*4)
    const int jq   = lane >> 4;          // batch-quad owner
    const int bt   = wl >> 4, hg = wl & 15, b0 = bt*16;

    // ---- stage weights ONCE, gate-major slots: slot rs=(w*8+rr) holds row
    //      r = (rr>>1)*256 + hg*16 + 2*w + (rr&1)  (g = rr>>1, ri = 2w+(rr&1))
    {
        const float* WI = w_ih + (size_t)l*G4H*H_;
        const float* WH = w_hh + (size_t)l*G4H*H_;
        float4* dst = (float4*)wlds;
        #pragma unroll
        for (int k = 0; k < 16; ++k) {                  // 8192 float4 / 512 thr
            const int idx = k*512 + tid;
            const int rs = idx >> 7, rem = idx & 127;
            const int m = rem >> 6, q4 = rem & 63;
            const int r = ((rs & 7) >> 1)*256 + hg*16 + 2*(rs >> 3) + (rs & 1);
            const float* src = (m ? WH : WI) + (size_t)r*H_;
            dst[idx] = ((const float4*)src)[q4];
        }
    }

    // ---- per-thread persistent state ----
    float bsum[8];                       // bias for my 8 rows (gate-major map)
    #pragma unroll
    for (int rr = 0; rr < 8; ++rr) {
        const int r = (rr >> 1)*256 + hg*16 + 2*w + (rr & 1);
        bsum[rr] = b_ih[(size_t)l*G4H + r] + b_hh[(size_t)l*G4H + r];
    }
    float4 wpr[3]; float wpb[3];         // head rows w, w+8, w+16 (L0 duty now)
    if (l == 0) {
        #pragma unroll
        for (int k = 0; k < 3; ++k) {
            const int a = w + 8*k;
            if (a < 19) {
                const float* wr = (a < 18) ? (Wp + (size_t)a*H_) : Wb;
                wpr[k] = ((const float4*)wr)[lane];
                wpb[k] = (a < 18) ? bp[a] : bb[0];
            }
        }
    }
    float cr = 0.f;                      // c for my (b,h): fixed thread mapping
    const int sb = b0 + (tid >> 5);      // batch of my staged 8-float chunk

    unsigned int* stamp = (unsigned int*)(ws + WS_CTR);
    __syncthreads();                     // weights staged

    for (int p = 0; p < 514; ++p) {
        const int t = p - l;
        const bool work   = (t >= 0 && t < T_);
        const bool dohead = (l == 0 && p >= 2);         // th = p-2 in [0,512)

        // ---- issue all sc loads up front (round trips overlap) ----
        float4 hh4;
        if (dohead)
            hh4 = cload4(ws + WS_H1 + (size_t)((p-2) & 1)*B_*H_ + (size_t)wl*H_ + lane*4);
        float4 ha, hb, xa, xb;
        if (work) {
            if (t == 0) {
                const float* src = h0in + (size_t)l*B_*H_ + (size_t)b0*H_ + tid*8;
                ha = ((const float4*)src)[0]; hb = ((const float4*)src)[1];
            } else {
                const float* src = ws + (l ? WS_H1 : WS_H0) + (size_t)((t-1)&1)*B_*H_
                                 + (size_t)b0*H_ + tid*8;
                ha = cload4(src); hb = cload4(src + 4);
            }
            if (l == 1) {
                const float* sx = ws + WS_H0 + (size_t)(t&1)*B_*H_ + (size_t)b0*H_ + tid*8;
                xa = cload4(sx); xb = cload4(sx + 4);
            }
        }

        // ---- head for th = p-2 (L0 WGs; h1 written 2 phases ago, same cluster) ----
        if (dohead) {
            const int th = p - 2;
            #pragma unroll
            for (int k = 0; k < 3; ++k) {
                const int a = w + 8*k;
                if (a < 19) {
                    float s = wpr[k].x*hh4.x + wpr[k].y*hh4.y + wpr[k].z*hh4.z + wpr[k].w*hh4.w;
                    s += __shfl_xor(s, 1);  s += __shfl_xor(s, 2);  s += __shfl_xor(s, 4);
                    s += __shfl_xor(s, 8);  s += __shfl_xor(s, 16); s += __shfl_xor(s, 32);
                    if (lane == 0) {
                        float v = s + wpb[k];
                        hlog[a] = v;
                        if (a < 18) out[((size_t)th*B_ + wl)*A_ + a] = v;
                        else        out[OUT_BASE + th*B_ + wl] = v;
                    }
                }
            }
        }

        // ---- staging + fragment reads ----
        float4 xr[4][4], hr[4][4];
        const float4* s4 = (const float4*)stg;
        if (work) {
            const float nd = done[t*B_ + sb] ? 0.f : 1.f;
            ha.x *= nd; ha.y *= nd; ha.z *= nd; ha.w *= nd;
            hb.x *= nd; hb.y *= nd; hb.z *= nd; hb.w *= nd;
            if (l == 1) {
                ((float4*)stg)[tid*2]     = xa;
                ((float4*)stg)[tid*2 + 1] = xb;
                __syncthreads();
                #pragma unroll
                for (int jj = 0; jj < 4; ++jj)
                    #pragma unroll
                    for (int q = 0; q < 4; ++q)
                        xr[jj][q] = s4[(jq*4 + jj)*64 + q*16 + kc];
                __syncthreads();                        // WAR before hr write
            } else {
                const float4* xb0 = (const float4*)(x + ((size_t)t*B_ + b0)*H_);
                #pragma unroll
                for (int jj = 0; jj < 4; ++jj)
                    #pragma unroll
                    for (int q = 0; q < 4; ++q)
                        xr[jj][q] = xb0[(size_t)(jq*4 + jj)*64 + q*16 + kc];
            }
            ((float4*)stg)[tid*2]     = ha;
            ((float4*)stg)[tid*2 + 1] = hb;
            __syncthreads();
            #pragma unroll
            for (int jj = 0; jj < 4; ++jj)
                #pragma unroll
                for (int q = 0; q < 4; ++q)
                    hr[jj][q] = s4[(jq*4 + jj)*64 + q*16 + kc];
        } else if (dohead) {
            __syncthreads();             // order hlog for argmax (p = 512, 513)
        }

        // ---- argmax (hlog complete; ordered by a sync above) ----
        if (dohead && tid == 0) {
            const int th = p - 2;
            float best = hlog[0]; int bi = 0;
            #pragma unroll
            for (int a = 1; a < A_; ++a) { float v = hlog[a]; if (v > best) { best = v; bi = a; } }
            out[OUT_ACT + th*B_ + wl] = (float)bi;       // strict > = first-max, matches np
        }

        // ---- FMA: 8 gate-major rows/wave; DPP reduce; capture my 4 gates ----
        float myg[4];
        if (work) {
            const float4* wl4 = (const float4*)wlds;
            const int kb = kc & 3;       // my batch-in-quad
            const int hs = kc >> 2;      // my hi parity (valid when kc<8)
            #pragma unroll
            for (int rr = 0; rr < 8; ++rr) {
                const int wb4 = (w*8 + rr)*128;          // 2 mats * 64 float4
                float4 wiv[4], whv[4];
                #pragma unroll
                for (int q = 0; q < 4; ++q) {
                    wiv[q] = wl4[wb4 + q*16 + kc];
                    whv[q] = wl4[wb4 + 64 + q*16 + kc];
                }
                float acc0 = 0.f, acc1 = 0.f, acc2 = 0.f, acc3 = 0.f;
                #pragma unroll
                for (int q = 0; q < 4; ++q) {
                    acc0 += wiv[q].x*xr[0][q].x + wiv[q].y*xr[0][q].y + wiv[q].z*xr[0][q].z + wiv[q].w*xr[0][q].w
                          + whv[q].x*hr[0][q].x + whv[q].y*hr[0][q].y + whv[q].z*hr[0][q].z + whv[q].w*hr[0][q].w;
                    acc1 += wiv[q].x*xr[1][q].x + wiv[q].y*xr[1][q].y + wiv[q].z*xr[1][q].z + wiv[q].w*xr[1][q].w
                          + whv[q].x*hr[1][q].x + whv[q].y*hr[1][q].y + whv[q].z*hr[1][q].z + whv[q].w*hr[1][q].w;
                    acc2 += wiv[q].x*xr[2][q].x + wiv[q].y*xr[2][q].y + wiv[q].z*xr[2][q].z + wiv[q].w*xr[2][q].w
                          + whv[q].x*hr[2][q].x + whv[q].y*hr[2][q].y + whv[q].z*hr[2][q].z + whv[q].w*hr[2][q].w;
                    acc3 += wiv[q].x*xr[3][q].x + wiv[q].y*xr[3][q].y + wiv[q].z*xr[3][q].z + wiv[q].w*xr[3][q].w
                          + whv[q].x*hr[3][q].x + whv[q].y*hr[3][q].y + whv[q].z*hr[3][q].z + whv[q].w*hr[3][q].w;
                }
                acc0 = rowsum16(acc0); acc1 = rowsum16(acc1);
                acc2 = rowsum16(acc2); acc3 = rowsum16(acc3);
                const float gsel = (kb == 0) ? acc0 : (kb == 1) ? acc1
                                 : (kb == 2) ? acc2 : acc3;
                if (hs == (rr & 1))
                    myg[rr >> 1] = gsel + bsum[rr];      // my (hi,b) row of gate rr>>1
            }
        }

        // ---- per-wave cell update (no barrier needed): lanes kc<8 own (b,hi) ----
        if (work && kc < 8) {
            const int b = b0 + jq*4 + (kc & 3);
            const int h = hg*16 + 2*w + (kc >> 2);
            const float nd = done[t*B_ + b] ? 0.f : 1.f;
            if (t == 0) cr = c0in[(size_t)l*B_*H_ + b*H_ + h];
            const float cp = cr * nd;
            const float ii = 1.f/(1.f + expf(-myg[0]));
            const float ff = 1.f/(1.f + expf(-myg[1]));
            const float gt = tanhf(myg[2]);
            const float oo = 1.f/(1.f + expf(-myg[3]));
            const float cl = ff*cp + ii*gt;
            cr = cl;
            if (t == T_-1)
                cswap(ws + (l ? WS_C1 : WS_C0) + (size_t)b*H_ + h, cl);
            float* hout = ws + (l ? WS_H1 : WS_H0) + (size_t)(t&1)*B_*H_;
            cswap(hout + (size_t)b*H_ + h, oo*tanhf(cl));
        }

        // ---- final state copy (synced by the p=512 barrier) ----
        if (l == 1 && p == 513 && tid < 256) {
            const int idx = wl*H_ + tid;
            out[OUT_HT + idx]         = cload(ws + WS_H0 + B_*H_ + idx);   // h0(511) parity 1
            out[OUT_HT + B_*H_ + idx] = cload(ws + WS_H1 + B_*H_ + idx);   // h1(511) parity 1
            out[OUT_CT + idx]         = cload(ws + WS_C0 + idx);
            out[OUT_CT + B_*H_ + idx] = cload(ws + WS_C1 + idx);
        }

        // ---- cluster barrier: swap-acked data, store-stamp arrival, 32-lane poll ----
        if (p < 513) {
            asm volatile("s_waitcnt vmcnt(0)" ::: "memory");   // swaps acked at L3
            __syncthreads();
            if (tid == 0)
                __hip_atomic_store(stamp + wg, (unsigned)(p + 1),
                                   __ATOMIC_RELAXED, __HIP_MEMORY_SCOPE_SYSTEM);
            if (tid < 32) {        // lane i polls member i of my 32-WG cluster
                const int cell = (tid < 16) ? (bt*16 + tid) : (128 + bt*16 + (tid - 16));
                while (__hip_atomic_load(stamp + cell, __ATOMIC_RELAXED,
                                         __HIP_MEMORY_SCOPE_SYSTEM) <= (unsigned)p)
                    __builtin_amdgcn_s_sleep(1);
            }
            __syncthreads();
        }
    }
}

extern "C" void kernel_launch(void* const* d_in, const int* in_sizes, int n_in,
                              void* d_out, int out_size, void* d_ws, size_t ws_size,
                              hipStream_t stream)
{
    const float* x    = (const float*)d_in[0];
    const int*   done = (const int*)  d_in[1];
    const float* h0   = (const float*)d_in[2];
    const float* c0   = (const float*)d_in[3];
    const float* w_ih = (const float*)d_in[4];
    const float* w_hh = (const float*)d_in[5];
    const float* b_ih = (const float*)d_in[6];
    const float* b_hh = (const float*)d_in[7];
    const float* Wp   = (const float*)d_in[8];
    const float* bp   = (const float*)d_in[9];
    const float* Wb   = (const float*)d_in[10];
    const float* bb   = (const float*)d_in[11];
    float* out = (float*)d_out;
    float* ws  = (float*)d_ws;    // 768 KB state + 1 KB stamp cells

    // zero the 256 stamp cells (captured node, re-runs every replay)
    hipMemsetAsync((char*)d_ws + (size_t)WS_CTR*sizeof(float), 0, 1024, stream);

    lstm_persist<<<dim3(256), dim3(512), 0, stream>>>(
        x, done, h0, c0, w_ih, w_hh, b_ih, b_hh, Wp, bp, Wb, bb, out, ws);
}

// Round 9
// 6653.445 us; speedup vs baseline: 1.1039x; 1.1039x over previous
//
#include <hip/hip_runtime.h>
#include <math.h>

#define T_  512
#define B_  128
#define H_  256
#define A_  18
#define G4H 1024
#define TB_ (T_*B_)

// d_out layout (floats): [logits T*B*A][baseline T*B][action T*B][hT 2*B*H][cT 2*B*H]
#define OUT_BASE  (TB_*A_)
#define OUT_ACT   (OUT_BASE + TB_)
#define OUT_HT    (OUT_ACT + TB_)
#define OUT_CT    (OUT_HT + 2*B_*H_)

// workspace (floats): double-buffered h per layer (parity = t&1), private c per layer,
// then 256 uint phase-stamp cells (one per WG, memset once per replay)
#define WS_H0  0
#define WS_H1  (2*B_*H_)
#define WS_C0  (4*B_*H_)
#define WS_C1  (5*B_*H_)
#define WS_CTR (6*B_*H_)

// SINGLE-DISPATCH PERSISTENT PIPELINE, v9 = v7 body + v8's safe wins.
// v8 post-mortem: gate-major per-wave cell update scattered the h/c swaps
// (8B granules -> 64B write transactions; WRITE_SIZE 146->549 MB, +800us).
// v9 reverts to v7's gates-LDS + tid<256 cell update (16 consecutive h per
// batch = 64B-coalesced swaps) and keeps from v8:
//   (1) DPP row_ror reduce (VALU) instead of ds_swizzle shuffles (frees DS
//       pipe shared with ds_read_b128 weight/fragment traffic);
//   (2) all sc loads issued up front (head h1 + recurrent h + L1's x) so
//       the L3 round trips overlap;
//   (3) head duty on L0 WGs (L1 pays double staging; balances the per-phase
//       straggler that the lockstep cluster barrier charges everyone).
// Sync skeleton unchanged from proven v6/v7: cross-WG data writes = returning
// atomic swaps (acked at the coherence point before vmcnt(0) clears),
// store-stamp arrival, 32-lane poll of the 32-WG dependency-closed cluster,
// no cache-maintenance instructions anywhere.

__device__ __forceinline__ float cload(const float* p) {
    return __hip_atomic_load((float*)p, __ATOMIC_RELAXED, __HIP_MEMORY_SCOPE_SYSTEM);
}
__device__ __forceinline__ float4 cload4(const float* p) {   // 16B-aligned
    union { unsigned long long u[2]; float4 f; } r;
    r.u[0] = __hip_atomic_load((const unsigned long long*)p,
                               __ATOMIC_RELAXED, __HIP_MEMORY_SCOPE_SYSTEM);
    r.u[1] = __hip_atomic_load((const unsigned long long*)(p + 2),
                               __ATOMIC_RELAXED, __HIP_MEMORY_SCOPE_SYSTEM);
    return r.f;
}
// ordered data write: atomic exchange, returning form forced by asm sink
__device__ __forceinline__ void cswap(float* p, float v) {
    float old = __hip_atomic_exchange(p, v, __ATOMIC_RELAXED, __HIP_MEMORY_SCOPE_SYSTEM);
    asm volatile("" :: "v"(old));
}
// DPP row_ror (within 16-lane rows); 4 rotation-adds = full 16-lane sum on VALU
template<int N>
__device__ __forceinline__ float ror16(float v) {
    return __int_as_float(__builtin_amdgcn_update_dpp(
        0, __float_as_int(v), 0x120 | N, 0xF, 0xF, true));
}
__device__ __forceinline__ float rowsum16(float v) {
    v += ror16<8>(v); v += ror16<4>(v); v += ror16<2>(v); v += ror16<1>(v);
    return v;   // every lane in the 16-row holds the total
}

__global__ __launch_bounds__(512, 1) void lstm_persist(
    const float* __restrict__ x, const int* __restrict__ done,
    const float* __restrict__ h0in, const float* __restrict__ c0in,
    const float* __restrict__ w_ih, const float* __restrict__ w_hh,
    const float* __restrict__ b_ih, const float* __restrict__ b_hh,
    const float* __restrict__ Wp, const float* __restrict__ bp,
    const float* __restrict__ Wb, const float* __restrict__ bb,
    float* __restrict__ out, float* __restrict__ ws)
{
    __shared__ __align__(16) float wlds[64*2*H_];      // 128 KB weight slice
    __shared__ __align__(16) float stg[16*H_];         // 16 KB activation stage
    __shared__ __align__(16) float gates[4][16][17];   // 4.25 KB
    __shared__ float hlog[19];
    // total ~148.4 KB < 160 KB; 1 WG/CU (required for co-residency)

    const int wg   = blockIdx.x;
    const int tid  = threadIdx.x;
    const int l    = wg >> 7;            // 0: layer0 (+head duty), 1: layer1
    const int wl   = wg & 127;
    const int lane = tid & 63;
    const int w    = tid >> 6;           // wave 0..7
    const int kc   = lane & 15;          // K-chunk owner (16 floats, k = q*64+kc*4)
    const int jq   = lane >> 4;          // batch-quad owner
    const int bt   = wl >> 4, hg = wl & 15, b0 = bt*16;

    // ---- stage weights ONCE: 64 gate rows x (wi,wh) -> LDS (v7 map) ----
    {
        const float* WI = w_ih + (size_t)l*G4H*H_;
        const float* WH = w_hh + (size_t)l*G4H*H_;
        float4* dst = (float4*)wlds;
        #pragma unroll
        for (int k = 0; k < 16; ++k) {                  // 8192 float4 / 512 thr
            const int idx = k*512 + tid;
            const int rs = idx >> 7, rem = idx & 127;
            const int m = rem >> 6, q4 = rem & 63;
            const int r = (rs >> 4)*256 + hg*16 + (rs & 15);
            const float* src = (m ? WH : WI) + (size_t)r*H_;
            dst[idx] = ((const float4*)src)[q4];
        }
    }

    // ---- per-thread persistent state ----
    float bsum[8];
    #pragma unroll
    for (int rr = 0; rr < 8; ++rr) {
        const int rs = w*8 + rr;
        const int r  = (rs >> 4)*256 + hg*16 + (rs & 15);
        bsum[rr] = b_ih[(size_t)l*G4H + r] + b_hh[(size_t)l*G4H + r];
    }
    float4 wpr[3]; float wpb[3];         // head rows w, w+8, w+16 (L0 duty)
    if (l == 0) {
        #pragma unroll
        for (int k = 0; k < 3; ++k) {
            const int a = w + 8*k;
            if (a < 19) {
                const float* wr = (a < 18) ? (Wp + (size_t)a*H_) : Wb;
                wpr[k] = ((const float4*)wr)[lane];
                wpb[k] = (a < 18) ? bp[a] : bb[0];
            }
        }
    }
    float cr = 0.f;                      // c for my (b,h) under tid<256 mapping
    const int sb = b0 + (tid >> 5);      // batch of my staged 8-float chunk

    unsigned int* stamp = (unsigned int*)(ws + WS_CTR);
    __syncthreads();                     // weights staged

    for (int p = 0; p < 514; ++p) {
        const int t = p - l;
        const bool work   = (t >= 0 && t < T_);
        const bool dohead = (l == 0 && p >= 2);         // th = p-2 in [0,512)

        // ---- issue all sc loads up front (L3 round trips overlap) ----
        float4 hh4;
        if (dohead)
            hh4 = cload4(ws + WS_H1 + (size_t)((p-2) & 1)*B_*H_ + (size_t)wl*H_ + lane*4);
        float4 ha, hb, xa, xb;
        if (work) {
            if (t == 0) {
                const float* src = h0in + (size_t)l*B_*H_ + (size_t)b0*H_ + tid*8;
                ha = ((const float4*)src)[0]; hb = ((const float4*)src)[1];
            } else {
                const float* src = ws + (l ? WS_H1 : WS_H0) + (size_t)((t-1)&1)*B_*H_
                                 + (size_t)b0*H_ + tid*8;
                ha = cload4(src); hb = cload4(src + 4);
            }
            if (l == 1) {
                const float* sx = ws + WS_H0 + (size_t)(t&1)*B_*H_ + (size_t)b0*H_ + tid*8;
                xa = cload4(sx); xb = cload4(sx + 4);
            }
        }

        // ---- head for th = p-2 (L0 WGs; h1 written 2 phases ago) ----
        if (dohead) {
            const int th = p - 2;
            #pragma unroll
            for (int k = 0; k < 3; ++k) {
                const int a = w + 8*k;
                if (a < 19) {
                    float s = wpr[k].x*hh4.x + wpr[k].y*hh4.y + wpr[k].z*hh4.z + wpr[k].w*hh4.w;
                    s += __shfl_xor(s, 1);  s += __shfl_xor(s, 2);  s += __shfl_xor(s, 4);
                    s += __shfl_xor(s, 8);  s += __shfl_xor(s, 16); s += __shfl_xor(s, 32);
                    if (lane == 0) {
                        float v = s + wpb[k];
                        hlog[a] = v;
                        if (a < 18) out[((size_t)th*B_ + wl)*A_ + a] = v;
                        else        out[OUT_BASE + th*B_ + wl] = v;
                    }
                }
            }
        }

        // ---- staging + fragment reads ----
        float4 xr[4][4], hr[4][4];
        const float4* s4 = (const float4*)stg;
        if (work) {
            const float nd = done[t*B_ + sb] ? 0.f : 1.f;
            ha.x *= nd; ha.y *= nd; ha.z *= nd; ha.w *= nd;
            hb.x *= nd; hb.y *= nd; hb.z *= nd; hb.w *= nd;
            if (l == 1) {
                ((float4*)stg)[tid*2]     = xa;
                ((float4*)stg)[tid*2 + 1] = xb;
                __syncthreads();
                #pragma unroll
                for (int jj = 0; jj < 4; ++jj)
                    #pragma unroll
                    for (int q = 0; q < 4; ++q)
                        xr[jj][q] = s4[(jq*4 + jj)*64 + q*16 + kc];
                __syncthreads();                        // WAR before hr write
            } else {
                const float4* xb0 = (const float4*)(x + ((size_t)t*B_ + b0)*H_);
                #pragma unroll
                for (int jj = 0; jj < 4; ++jj)
                    #pragma unroll
                    for (int q = 0; q < 4; ++q)
                        xr[jj][q] = xb0[(size_t)(jq*4 + jj)*64 + q*16 + kc];
            }
            ((float4*)stg)[tid*2]     = ha;
            ((float4*)stg)[tid*2 + 1] = hb;
            __syncthreads();
            #pragma unroll
            for (int jj = 0; jj < 4; ++jj)
                #pragma unroll
                for (int q = 0; q < 4; ++q)
                    hr[jj][q] = s4[(jq*4 + jj)*64 + q*16 + kc];

            // -- FMA: 8 rows per wave (v7 map), weights from LDS, DPP reduce --
            const float4* wl4 = (const float4*)wlds;
            #pragma unroll 2
            for (int rr = 0; rr < 8; ++rr) {
                const int rs = w*8 + rr;
                const int g  = rs >> 4, ri = rs & 15;
                const int wb4 = rs*128;
                float4 wiv[4], whv[4];
                #pragma unroll
                for (int q = 0; q < 4; ++q) {
                    wiv[q] = wl4[wb4 + q*16 + kc];
                    whv[q] = wl4[wb4 + 64 + q*16 + kc];
                }
                float acc0 = 0.f, acc1 = 0.f, acc2 = 0.f, acc3 = 0.f;
                #pragma unroll
                for (int q = 0; q < 4; ++q) {
                    acc0 += wiv[q].x*xr[0][q].x + wiv[q].y*xr[0][q].y + wiv[q].z*xr[0][q].z + wiv[q].w*xr[0][q].w
                          + whv[q].x*hr[0][q].x + whv[q].y*hr[0][q].y + whv[q].z*hr[0][q].z + whv[q].w*hr[0][q].w;
                    acc1 += wiv[q].x*xr[1][q].x + wiv[q].y*xr[1][q].y + wiv[q].z*xr[1][q].z + wiv[q].w*xr[1][q].w
                          + whv[q].x*hr[1][q].x + whv[q].y*hr[1][q].y + whv[q].z*hr[1][q].z + whv[q].w*hr[1][q].w;
                    acc2 += wiv[q].x*xr[2][q].x + wiv[q].y*xr[2][q].y + wiv[q].z*xr[2][q].z + wiv[q].w*xr[2][q].w
                          + whv[q].x*hr[2][q].x + whv[q].y*hr[2][q].y + whv[q].z*hr[2][q].z + whv[q].w*hr[2][q].w;
                    acc3 += wiv[q].x*xr[3][q].x + wiv[q].y*xr[3][q].y + wiv[q].z*xr[3][q].z + wiv[q].w*xr[3][q].w
                          + whv[q].x*hr[3][q].x + whv[q].y*hr[3][q].y + whv[q].z*hr[3][q].z + whv[q].w*hr[3][q].w;
                }
                acc0 = rowsum16(acc0); acc1 = rowsum16(acc1);
                acc2 = rowsum16(acc2); acc3 = rowsum16(acc3);
                const float v = (kc == 0) ? acc0 : (kc == 1) ? acc1
                              : (kc == 2) ? acc2 : acc3;
                if (kc < 4)
                    gates[g][ri][jq*4 + kc] = v + bsum[rr];
            }
        }

        __syncthreads();          // gates ready (uniform; also orders hlog)

        // ---- cell update: tid<256, consecutive h -> 64B-coalesced swaps ----
        if (work && tid < 256) {
            const int j = tid >> 4, hi = tid & 15;
            const int b = b0 + j, h = hg*16 + hi;
            const float nd = done[t*B_ + b] ? 0.f : 1.f;
            if (t == 0) cr = c0in[(size_t)l*B_*H_ + b*H_ + h];
            const float cp = cr * nd;
            const float gi = gates[0][hi][j], gf = gates[1][hi][j];
            const float gv = gates[2][hi][j], go = gates[3][hi][j];
            const float ii = 1.f/(1.f + expf(-gi));
            const float ff = 1.f/(1.f + expf(-gf));
            const float gt = tanhf(gv);
            const float oo = 1.f/(1.f + expf(-go));
            const float cl = ff*cp + ii*gt;
            cr = cl;
            if (t == T_-1)
                cswap(ws + (l ? WS_C1 : WS_C0) + (size_t)b*H_ + h, cl);
            float* hout = ws + (l ? WS_H1 : WS_H0) + (size_t)(t&1)*B_*H_;
            cswap(hout + (size_t)b*H_ + h, oo*tanhf(cl));
        }

        // ---- argmax (hlog complete; ordered by the sync above) ----
        if (dohead && tid == 0) {
            const int th = p - 2;
            float best = hlog[0]; int bi = 0;
            #pragma unroll
            for (int a = 1; a < A_; ++a) { float v = hlog[a]; if (v > best) { best = v; bi = a; } }
            out[OUT_ACT + th*B_ + wl] = (float)bi;       // strict > = first-max, matches np
        }

        // ---- final state copy (synced by the p=512 barrier) ----
        if (l == 1 && p == 513 && tid < 256) {
            const int idx = wl*H_ + tid;
            out[OUT_HT + idx]         = cload(ws + WS_H0 + B_*H_ + idx);   // h0(511) parity 1
            out[OUT_HT + B_*H_ + idx] = cload(ws + WS_H1 + B_*H_ + idx);   // h1(511) parity 1
            out[OUT_CT + idx]         = cload(ws + WS_C0 + idx);
            out[OUT_CT + B_*H_ + idx] = cload(ws + WS_C1 + idx);
        }

        // ---- cluster barrier: swap-acked data, store-stamp arrival, 32-lane poll ----
        if (p < 513) {
            asm volatile("s_waitcnt vmcnt(0)" ::: "memory");   // swaps acked at L3
            __syncthreads();
            if (tid == 0)
                __hip_atomic_store(stamp + wg, (unsigned)(p + 1),
                                   __ATOMIC_RELAXED, __HIP_MEMORY_SCOPE_SYSTEM);
            if (tid < 32) {        // lane i polls member i of my 32-WG cluster
                const int cell = (tid < 16) ? (bt*16 + tid) : (128 + bt*16 + (tid - 16));
                while (__hip_atomic_load(stamp + cell, __ATOMIC_RELAXED,
                                         __HIP_MEMORY_SCOPE_SYSTEM) <= (unsigned)p)
                    __builtin_amdgcn_s_sleep(1);
            }
            __syncthreads();
        }
    }
}

extern "C" void kernel_launch(void* const* d_in, const int* in_sizes, int n_in,
                              void* d_out, int out_size, void* d_ws, size_t ws_size,
                              hipStream_t stream)
{
    const float* x    = (const float*)d_in[0];
    const int*   done = (const int*)  d_in[1];
    const float* h0   = (const float*)d_in[2];
    const float* c0   = (const float*)d_in[3];
    const float* w_ih = (const float*)d_in[4];
    const float* w_hh = (const float*)d_in[5];
    const float* b_ih = (const float*)d_in[6];
    const float* b_hh = (const float*)d_in[7];
    const float* Wp   = (const float*)d_in[8];
    const float* bp   = (const float*)d_in[9];
    const float* Wb   = (const float*)d_in[10];
    const float* bb   = (const float*)d_in[11];
    float* out = (float*)d_out;
    float* ws  = (float*)d_ws;    // 768 KB state + 1 KB stamp cells

    // zero the 256 stamp cells (captured node, re-runs every replay)
    hipMemsetAsync((char*)d_ws + (size_t)WS_CTR*sizeof(float), 0, 1024, stream);

    lstm_persist<<<dim3(256), dim3(512), 0, stream>>>(
        x, done, h0, c0, w_ih, w_hh, b_ih, b_hh, Wp, bp, Wb, bb, out, ws);
}

// Round 10
// 6535.899 us; speedup vs baseline: 1.1238x; 1.0180x over previous
//
#include <hip/hip_runtime.h>
#include <math.h>

#define T_  512
#define B_  128
#define H_  256
#define A_  18
#define G4H 1024
#define TB_ (T_*B_)

// d_out layout (floats): [logits T*B*A][baseline T*B][action T*B][hT 2*B*H][cT 2*B*H]
#define OUT_BASE  (TB_*A_)
#define OUT_ACT   (OUT_BASE + TB_)
#define OUT_HT    (OUT_ACT + TB_)
#define OUT_CT    (OUT_HT + 2*B_*H_)

// workspace (floats): PARITY-4 h per layer (slot = t&3), private c per layer,
// then 256 uint phase-stamp cells (one per WG, memset once per replay). 1.31 MB.
#define WS_H0  0                  // [4][B][H]
#define WS_H1  (4*B_*H_)          // [4][B][H]
#define WS_C0  (8*B_*H_)
#define WS_C1  (9*B_*H_)
#define WS_CTR (10*B_*H_)

// SINGLE-DISPATCH DECOUPLED-LAYER PIPELINE, v10.
// v9 post-mortem: body optimizations were null (bank-conflict counter bit-
// identical) -> the 13 us phase floor is the LOCKSTEP: 32 WGs pay
// max(L0,L1 body) + straggler-amplified barrier every phase. Dependency
// analysis: L0 needs L1 only through a WAR constraint (don't overwrite
// h0(t-4) before L1 consumed it). With parity-4 h buffers L0 may run ~3
// phases ahead. Decoupled polls:
//   L0 end of phase p: own L0 cluster >= p+1, L1 cluster >= p-1 (lag-2)
//   L1 end of phase p: own L1 cluster >= p+1, L0 cluster >= p+1 (auto: ahead)
// Head moves to lag-4 (th = p-4; h1(p-4) written by L1 in phase p-3, which
// the lag-2 poll guarantees). 516 phases. Steady-state wall = L1's own loop
// (16-WG convoy) instead of max(L0,L1) over 32 WGs. Sync primitives are the
// v6-v9 proven ones: cross-WG data writes = returning atomic swaps (acked at
// the L3 coherence point before vmcnt(0) clears), store-stamp arrival,
// relaxed system-scope polls, no cache-maintenance instructions anywhere.

__device__ __forceinline__ float cload(const float* p) {
    return __hip_atomic_load((float*)p, __ATOMIC_RELAXED, __HIP_MEMORY_SCOPE_SYSTEM);
}
__device__ __forceinline__ float4 cload4(const float* p) {   // 16B-aligned
    union { unsigned long long u[2]; float4 f; } r;
    r.u[0] = __hip_atomic_load((const unsigned long long*)p,
                               __ATOMIC_RELAXED, __HIP_MEMORY_SCOPE_SYSTEM);
    r.u[1] = __hip_atomic_load((const unsigned long long*)(p + 2),
                               __ATOMIC_RELAXED, __HIP_MEMORY_SCOPE_SYSTEM);
    return r.f;
}
// ordered data write: atomic exchange, returning form forced by asm sink
__device__ __forceinline__ void cswap(float* p, float v) {
    float old = __hip_atomic_exchange(p, v, __ATOMIC_RELAXED, __HIP_MEMORY_SCOPE_SYSTEM);
    asm volatile("" :: "v"(old));
}
// DPP row_ror (within 16-lane rows); 4 rotation-adds = full 16-lane sum on VALU
template<int N>
__device__ __forceinline__ float ror16(float v) {
    return __int_as_float(__builtin_amdgcn_update_dpp(
        0, __float_as_int(v), 0x120 | N, 0xF, 0xF, true));
}
__device__ __forceinline__ float rowsum16(float v) {
    v += ror16<8>(v); v += ror16<4>(v); v += ror16<2>(v); v += ror16<1>(v);
    return v;
}

__global__ __launch_bounds__(512, 1) void lstm_persist(
    const float* __restrict__ x, const int* __restrict__ done,
    const float* __restrict__ h0in, const float* __restrict__ c0in,
    const float* __restrict__ w_ih, const float* __restrict__ w_hh,
    const float* __restrict__ b_ih, const float* __restrict__ b_hh,
    const float* __restrict__ Wp, const float* __restrict__ bp,
    const float* __restrict__ Wb, const float* __restrict__ bb,
    float* __restrict__ out, float* __restrict__ ws)
{
    __shared__ __align__(16) float wlds[64*2*H_];      // 128 KB weight slice
    __shared__ __align__(16) float stg[16*H_];         // 16 KB activation stage
    __shared__ __align__(16) float gates[4][16][17];   // 4.25 KB
    __shared__ float hlog[19];
    // total ~148.4 KB < 160 KB; 1 WG/CU (required for co-residency)

    const int wg   = blockIdx.x;
    const int tid  = threadIdx.x;
    const int l    = wg >> 7;            // 0: layer0 (+head duty), 1: layer1
    const int wl   = wg & 127;
    const int lane = tid & 63;
    const int w    = tid >> 6;           // wave 0..7
    const int kc   = lane & 15;          // K-chunk owner (16 floats, k = q*64+kc*4)
    const int jq   = lane >> 4;          // batch-quad owner
    const int bt   = wl >> 4, hg = wl & 15, b0 = bt*16;

    // ---- stage weights ONCE: 64 gate rows x (wi,wh) -> LDS ----
    {
        const float* WI = w_ih + (size_t)l*G4H*H_;
        const float* WH = w_hh + (size_t)l*G4H*H_;
        float4* dst = (float4*)wlds;
        #pragma unroll
        for (int k = 0; k < 16; ++k) {                  // 8192 float4 / 512 thr
            const int idx = k*512 + tid;
            const int rs = idx >> 7, rem = idx & 127;
            const int m = rem >> 6, q4 = rem & 63;
            const int r = (rs >> 4)*256 + hg*16 + (rs & 15);
            const float* src = (m ? WH : WI) + (size_t)r*H_;
            dst[idx] = ((const float4*)src)[q4];
        }
    }

    // ---- per-thread persistent state ----
    float bsum[8];
    #pragma unroll
    for (int rr = 0; rr < 8; ++rr) {
        const int rs = w*8 + rr;
        const int r  = (rs >> 4)*256 + hg*16 + (rs & 15);
        bsum[rr] = b_ih[(size_t)l*G4H + r] + b_hh[(size_t)l*G4H + r];
    }
    float4 wpr[3]; float wpb[3];         // head rows w, w+8, w+16 (L0 duty)
    if (l == 0) {
        #pragma unroll
        for (int k = 0; k < 3; ++k) {
            const int a = w + 8*k;
            if (a < 19) {
                const float* wr = (a < 18) ? (Wp + (size_t)a*H_) : Wb;
                wpr[k] = ((const float4*)wr)[lane];
                wpb[k] = (a < 18) ? bp[a] : bb[0];
            }
        }
    }
    float cr = 0.f;                      // c for my (b,h) under tid<256 mapping
    const int sb = b0 + (tid >> 5);      // batch of my staged 8-float chunk

    unsigned int* stamp = (unsigned int*)(ws + WS_CTR);
    __syncthreads();                     // weights staged

    for (int p = 0; p < 516; ++p) {
        const int t = p - l;
        const bool work   = (t >= 0 && t < T_);
        const bool dohead = (l == 0 && p >= 4);         // th = p-4 in [0,512)

        // ---- issue all sc loads up front (L3 round trips overlap) ----
        float4 hh4;
        if (dohead)
            hh4 = cload4(ws + WS_H1 + (size_t)((p-4) & 3)*B_*H_ + (size_t)wl*H_ + lane*4);
        float4 ha, hb, xa, xb;
        if (work) {
            if (t == 0) {
                const float* src = h0in + (size_t)l*B_*H_ + (size_t)b0*H_ + tid*8;
                ha = ((const float4*)src)[0]; hb = ((const float4*)src)[1];
            } else {
                const float* src = ws + (l ? WS_H1 : WS_H0) + (size_t)((t-1)&3)*B_*H_
                                 + (size_t)b0*H_ + tid*8;
                ha = cload4(src); hb = cload4(src + 4);
            }
            if (l == 1) {
                const float* sx = ws + WS_H0 + (size_t)(t&3)*B_*H_ + (size_t)b0*H_ + tid*8;
                xa = cload4(sx); xb = cload4(sx + 4);
            }
        }

        // ---- head for th = p-4 (L0 WGs; h1 written >=3 phases ago) ----
        if (dohead) {
            const int th = p - 4;
            #pragma unroll
            for (int k = 0; k < 3; ++k) {
                const int a = w + 8*k;
                if (a < 19) {
                    float s = wpr[k].x*hh4.x + wpr[k].y*hh4.y + wpr[k].z*hh4.z + wpr[k].w*hh4.w;
                    s += __shfl_xor(s, 1);  s += __shfl_xor(s, 2);  s += __shfl_xor(s, 4);
                    s += __shfl_xor(s, 8);  s += __shfl_xor(s, 16); s += __shfl_xor(s, 32);
                    if (lane == 0) {
                        float v = s + wpb[k];
                        hlog[a] = v;
                        if (a < 18) out[((size_t)th*B_ + wl)*A_ + a] = v;
                        else        out[OUT_BASE + th*B_ + wl] = v;
                    }
                }
            }
        }

        // ---- staging + fragment reads + FMA ----
        const float4* s4 = (const float4*)stg;
        if (work) {
            float4 xr[4][4], hr[4][4];
            const float nd = done[t*B_ + sb] ? 0.f : 1.f;
            ha.x *= nd; ha.y *= nd; ha.z *= nd; ha.w *= nd;
            hb.x *= nd; hb.y *= nd; hb.z *= nd; hb.w *= nd;
            if (l == 1) {
                ((float4*)stg)[tid*2]     = xa;
                ((float4*)stg)[tid*2 + 1] = xb;
                __syncthreads();
                #pragma unroll
                for (int jj = 0; jj < 4; ++jj)
                    #pragma unroll
                    for (int q = 0; q < 4; ++q)
                        xr[jj][q] = s4[(jq*4 + jj)*64 + q*16 + kc];
                __syncthreads();                        // WAR before hr write
            } else {
                const float4* xb0 = (const float4*)(x + ((size_t)t*B_ + b0)*H_);
                #pragma unroll
                for (int jj = 0; jj < 4; ++jj)
                    #pragma unroll
                    for (int q = 0; q < 4; ++q)
                        xr[jj][q] = xb0[(size_t)(jq*4 + jj)*64 + q*16 + kc];
            }
            ((float4*)stg)[tid*2]     = ha;
            ((float4*)stg)[tid*2 + 1] = hb;
            __syncthreads();
            #pragma unroll
            for (int jj = 0; jj < 4; ++jj)
                #pragma unroll
                for (int q = 0; q < 4; ++q)
                    hr[jj][q] = s4[(jq*4 + jj)*64 + q*16 + kc];

            const float4* wl4 = (const float4*)wlds;
            #pragma unroll 2
            for (int rr = 0; rr < 8; ++rr) {
                const int rs = w*8 + rr;
                const int g  = rs >> 4, ri = rs & 15;
                const int wb4 = rs*128;
                float4 wiv[4], whv[4];
                #pragma unroll
                for (int q = 0; q < 4; ++q) {
                    wiv[q] = wl4[wb4 + q*16 + kc];
                    whv[q] = wl4[wb4 + 64 + q*16 + kc];
                }
                float acc0 = 0.f, acc1 = 0.f, acc2 = 0.f, acc3 = 0.f;
                #pragma unroll
                for (int q = 0; q < 4; ++q) {
                    acc0 += wiv[q].x*xr[0][q].x + wiv[q].y*xr[0][q].y + wiv[q].z*xr[0][q].z + wiv[q].w*xr[0][q].w
                          + whv[q].x*hr[0][q].x + whv[q].y*hr[0][q].y + whv[q].z*hr[0][q].z + whv[q].w*hr[0][q].w;
                    acc1 += wiv[q].x*xr[1][q].x + wiv[q].y*xr[1][q].y + wiv[q].z*xr[1][q].z + wiv[q].w*xr[1][q].w
                          + whv[q].x*hr[1][q].x + whv[q].y*hr[1][q].y + whv[q].z*hr[1][q].z + whv[q].w*hr[1][q].w;
                    acc2 += wiv[q].x*xr[2][q].x + wiv[q].y*xr[2][q].y + wiv[q].z*xr[2][q].z + wiv[q].w*xr[2][q].w
                          + whv[q].x*hr[2][q].x + whv[q].y*hr[2][q].y + whv[q].z*hr[2][q].z + whv[q].w*hr[2][q].w;
                    acc3 += wiv[q].x*xr[3][q].x + wiv[q].y*xr[3][q].y + wiv[q].z*xr[3][q].z + wiv[q].w*xr[3][q].w
                          + whv[q].x*hr[3][q].x + whv[q].y*hr[3][q].y + whv[q].z*hr[3][q].z + whv[q].w*hr[3][q].w;
                }
                acc0 = rowsum16(acc0); acc1 = rowsum16(acc1);
                acc2 = rowsum16(acc2); acc3 = rowsum16(acc3);
                const float v = (kc == 0) ? acc0 : (kc == 1) ? acc1
                              : (kc == 2) ? acc2 : acc3;
                if (kc < 4)
                    gates[g][ri][jq*4 + kc] = v + bsum[rr];
            }
        }

        __syncthreads();          // gates ready; also orders hlog for argmax

        // ---- cell update: tid<256, consecutive h -> 64B-coalesced swaps ----
        if (work && tid < 256) {
            const int j = tid >> 4, hi = tid & 15;
            const int b = b0 + j, h = hg*16 + hi;
            const float nd = done[t*B_ + b] ? 0.f : 1.f;
            if (t == 0) cr = c0in[(size_t)l*B_*H_ + b*H_ + h];
            const float cp = cr * nd;
            const float gi = gates[0][hi][j], gf = gates[1][hi][j];
            const float gv = gates[2][hi][j], go = gates[3][hi][j];
            const float ii = 1.f/(1.f + expf(-gi));
            const float ff = 1.f/(1.f + expf(-gf));
            const float gt = tanhf(gv);
            const float oo = 1.f/(1.f + expf(-go));
            const float cl = ff*cp + ii*gt;
            cr = cl;
            if (t == T_-1)
                cswap(ws + (l ? WS_C1 : WS_C0) + (size_t)b*H_ + h, cl);
            float* hout = ws + (l ? WS_H1 : WS_H0) + (size_t)(t&3)*B_*H_;
            cswap(hout + (size_t)b*H_ + h, oo*tanhf(cl));
        }

        // ---- argmax (hlog complete; ordered by the sync above) ----
        if (dohead && tid == 0) {
            const int th = p - 4;
            float best = hlog[0]; int bi = 0;
            #pragma unroll
            for (int a = 1; a < A_; ++a) { float v = hlog[a]; if (v > best) { best = v; bi = a; } }
            out[OUT_ACT + th*B_ + wl] = (float)bi;       // strict > = first-max, matches np
        }

        // ---- final state copy (L1, p=513: polls guaranteed L0>=513, L1>=513) ----
        if (l == 1 && p == 513 && tid < 256) {
            const int idx = wl*H_ + tid;
            out[OUT_HT + idx]         = cload(ws + WS_H0 + 3*B_*H_ + idx);   // h0(511) slot 3
            out[OUT_HT + B_*H_ + idx] = cload(ws + WS_H1 + 3*B_*H_ + idx);   // h1(511) slot 3
            out[OUT_CT + idx]         = cload(ws + WS_C0 + idx);
            out[OUT_CT + B_*H_ + idx] = cload(ws + WS_C1 + idx);
        }

        // ---- decoupled cluster barrier ----
        if (p < 515) {
            asm volatile("s_waitcnt vmcnt(0)" ::: "memory");   // swaps acked at L3
            __syncthreads();
            if (tid == 0)
                __hip_atomic_store(stamp + wg, (unsigned)(p + 1),
                                   __ATOMIC_RELAXED, __HIP_MEMORY_SCOPE_SYSTEM);
            if (tid < 32) {
                const bool own = (tid < 16);
                const int  i   = tid & 15;
                const int  cell = (own ? l : (1 - l))*128 + bt*16 + i;
                // L0: own >= p+1, L1 (other) >= p-1 (lag-2). L1: both >= p+1.
                const int tgt = own ? (p + 1) : ((l == 0) ? (p - 1) : (p + 1));
                if (tgt > 0)
                    while (__hip_atomic_load(stamp + cell, __ATOMIC_RELAXED,
                                             __HIP_MEMORY_SCOPE_SYSTEM) < (unsigned)tgt)
                        __builtin_amdgcn_s_sleep(1);
            }
            __syncthreads();
        }
    }
}

extern "C" void kernel_launch(void* const* d_in, const int* in_sizes, int n_in,
                              void* d_out, int out_size, void* d_ws, size_t ws_size,
                              hipStream_t stream)
{
    const float* x    = (const float*)d_in[0];
    const int*   done = (const int*)  d_in[1];
    const float* h0   = (const float*)d_in[2];
    const float* c0   = (const float*)d_in[3];
    const float* w_ih = (const float*)d_in[4];
    const float* w_hh = (const float*)d_in[5];
    const float* b_ih = (const float*)d_in[6];
    const float* b_hh = (const float*)d_in[7];
    const float* Wp   = (const float*)d_in[8];
    const float* bp   = (const float*)d_in[9];
    const float* Wb   = (const float*)d_in[10];
    const float* bb   = (const float*)d_in[11];
    float* out = (float*)d_out;
    float* ws  = (float*)d_ws;    // 1.31 MB state + 1 KB stamp cells

    // zero the 256 stamp cells (captured node, re-runs every replay)
    hipMemsetAsync((char*)d_ws + (size_t)WS_CTR*sizeof(float), 0, 1024, stream);

    lstm_persist<<<dim3(256), dim3(512), 0, stream>>>(
        x, done, h0, c0, w_ih, w_hh, b_ih, b_hh, Wp, bp, Wb, bb, out, ws);
}

// Round 11
// 5673.675 us; speedup vs baseline: 1.2946x; 1.1520x over previous
//
#include <hip/hip_runtime.h>
#include <math.h>

#define T_  512
#define B_  128
#define H_  256
#define A_  18
#define G4H 1024
#define TB_ (T_*B_)

// d_out layout (floats): [logits T*B*A][baseline T*B][action T*B][hT 2*B*H][cT 2*B*H]
#define OUT_BASE  (TB_*A_)
#define OUT_ACT   (OUT_BASE + TB_)
#define OUT_HT    (OUT_ACT + TB_)
#define OUT_CT    (OUT_HT + 2*B_*H_)

// workspace (floats): PARITY-4 h per layer (slot = t&3), private c per layer,
// then 256 uint phase-stamp cells (one per WG, memset once per replay). 1.31 MB.
#define WS_H0  0                  // [4][B][H]
#define WS_H1  (4*B_*H_)          // [4][B][H]
#define WS_C0  (8*B_*H_)
#define WS_C1  (9*B_*H_)
#define WS_CTR (10*B_*H_)

// SINGLE-DISPATCH DECOUPLED-LAYER PIPELINE, v11.
// v9/v10 post-mortem: body + decoupling changes all null at ~12.7 us/phase.
// Recount: xr[4][4]+hr[4][4] = 128 VGPRs of fragments but VGPR_Count=128 total
// -> compiler was REMATERIALIZING the LDS fragment reads inside the row loop.
// ~320 ds_read_b128/thread x 8 waves x 12 cyc = 12.8 us = the exact phase time:
// the phase was LDS-pipe-bound on redundant reads. Fix, compiler-proof:
//   (a) x-fragments are read BEFORE stg is overwritten with h (barrier between)
//       -> re-reading after the clobber is illegal -> they MUST stay in VGPRs;
//   (b) h is processed in 2 batch-passes (2 batches each): only 8 h-frag + 8
//       weight float4 live per pass (~135 VGPR total) -> no pressure to spill;
//       weights re-read per pass (broadcast, cheap) to buy that.
//   (c) row loop fully unrolled; every fragment index compile-time constant.
// DS reads/thread ~320 -> ~160 (ideal 96). Everything else is v10 verbatim:
// decoupled parity-4 pipeline, returning-swap data writes (acked at the L3
// coherence point before vmcnt(0) clears), store-stamp arrival, relaxed
// system-scope polls, no cache-maintenance instructions.

__device__ __forceinline__ float cload(const float* p) {
    return __hip_atomic_load((float*)p, __ATOMIC_RELAXED, __HIP_MEMORY_SCOPE_SYSTEM);
}
__device__ __forceinline__ float4 cload4(const float* p) {   // 16B-aligned
    union { unsigned long long u[2]; float4 f; } r;
    r.u[0] = __hip_atomic_load((const unsigned long long*)p,
                               __ATOMIC_RELAXED, __HIP_MEMORY_SCOPE_SYSTEM);
    r.u[1] = __hip_atomic_load((const unsigned long long*)(p + 2),
                               __ATOMIC_RELAXED, __HIP_MEMORY_SCOPE_SYSTEM);
    return r.f;
}
// ordered data write: atomic exchange, returning form forced by asm sink
__device__ __forceinline__ void cswap(float* p, float v) {
    float old = __hip_atomic_exchange(p, v, __ATOMIC_RELAXED, __HIP_MEMORY_SCOPE_SYSTEM);
    asm volatile("" :: "v"(old));
}
// DPP row_ror (within 16-lane rows); 4 rotation-adds = full 16-lane sum on VALU
template<int N>
__device__ __forceinline__ float ror16(float v) {
    return __int_as_float(__builtin_amdgcn_update_dpp(
        0, __float_as_int(v), 0x120 | N, 0xF, 0xF, true));
}
__device__ __forceinline__ float rowsum16(float v) {
    v += ror16<8>(v); v += ror16<4>(v); v += ror16<2>(v); v += ror16<1>(v);
    return v;
}

__global__ __launch_bounds__(512, 1) void lstm_persist(
    const float* __restrict__ x, const int* __restrict__ done,
    const float* __restrict__ h0in, const float* __restrict__ c0in,
    const float* __restrict__ w_ih, const float* __restrict__ w_hh,
    const float* __restrict__ b_ih, const float* __restrict__ b_hh,
    const float* __restrict__ Wp, const float* __restrict__ bp,
    const float* __restrict__ Wb, const float* __restrict__ bb,
    float* __restrict__ out, float* __restrict__ ws)
{
    __shared__ __align__(16) float wlds[64*2*H_];      // 128 KB weight slice
    __shared__ __align__(16) float stg[16*H_];         // 16 KB activation stage
    __shared__ __align__(16) float gates[4][16][17];   // 4.25 KB
    __shared__ float hlog[19];
    // total ~148.4 KB < 160 KB; 1 WG/CU (required for co-residency)

    const int wg   = blockIdx.x;
    const int tid  = threadIdx.x;
    const int l    = wg >> 7;            // 0: layer0 (+head duty), 1: layer1
    const int wl   = wg & 127;
    const int lane = tid & 63;
    const int w    = tid >> 6;           // wave 0..7
    const int kc   = lane & 15;          // K-chunk owner (16 floats, k = q*64+kc*4)
    const int jq   = lane >> 4;          // batch-quad owner
    const int bt   = wl >> 4, hg = wl & 15, b0 = bt*16;

    // ---- stage weights ONCE: 64 gate rows x (wi,wh) -> LDS ----
    {
        const float* WI = w_ih + (size_t)l*G4H*H_;
        const float* WH = w_hh + (size_t)l*G4H*H_;
        float4* dst = (float4*)wlds;
        #pragma unroll
        for (int k = 0; k < 16; ++k) {                  // 8192 float4 / 512 thr
            const int idx = k*512 + tid;
            const int rs = idx >> 7, rem = idx & 127;
            const int m = rem >> 6, q4 = rem & 63;
            const int r = (rs >> 4)*256 + hg*16 + (rs & 15);
            const float* src = (m ? WH : WI) + (size_t)r*H_;
            dst[idx] = ((const float4*)src)[q4];
        }
    }

    // ---- per-thread persistent state ----
    float bsum[8];
    #pragma unroll
    for (int rr = 0; rr < 8; ++rr) {
        const int rs = w*8 + rr;
        const int r  = (rs >> 4)*256 + hg*16 + (rs & 15);
        bsum[rr] = b_ih[(size_t)l*G4H + r] + b_hh[(size_t)l*G4H + r];
    }
    float4 wpr[3]; float wpb[3];         // head rows w, w+8, w+16 (L0 duty)
    if (l == 0) {
        #pragma unroll
        for (int k = 0; k < 3; ++k) {
            const int a = w + 8*k;
            if (a < 19) {
                const float* wr = (a < 18) ? (Wp + (size_t)a*H_) : Wb;
                wpr[k] = ((const float4*)wr)[lane];
                wpb[k] = (a < 18) ? bp[a] : bb[0];
            }
        }
    }
    float cr = 0.f;                      // c for my (b,h) under tid<256 mapping
    const int sb = b0 + (tid >> 5);      // batch of my staged 8-float chunk

    unsigned int* stamp = (unsigned int*)(ws + WS_CTR);
    __syncthreads();                     // weights staged

    for (int p = 0; p < 516; ++p) {
        const int t = p - l;
        const bool work   = (t >= 0 && t < T_);
        const bool dohead = (l == 0 && p >= 4);         // th = p-4 in [0,512)

        // ---- issue all sc loads up front (L3 round trips overlap) ----
        float4 hh4;
        if (dohead)
            hh4 = cload4(ws + WS_H1 + (size_t)((p-4) & 3)*B_*H_ + (size_t)wl*H_ + lane*4);
        float4 ha, hb, xa, xb;
        if (work) {
            if (t == 0) {
                const float* src = h0in + (size_t)l*B_*H_ + (size_t)b0*H_ + tid*8;
                ha = ((const float4*)src)[0]; hb = ((const float4*)src)[1];
            } else {
                const float* src = ws + (l ? WS_H1 : WS_H0) + (size_t)((t-1)&3)*B_*H_
                                 + (size_t)b0*H_ + tid*8;
                ha = cload4(src); hb = cload4(src + 4);
            }
            if (l == 1) {
                const float* sx = ws + WS_H0 + (size_t)(t&3)*B_*H_ + (size_t)b0*H_ + tid*8;
                xa = cload4(sx); xb = cload4(sx + 4);
            }
        }

        // ---- head for th = p-4 (L0 WGs; h1 written >=3 phases ago) ----
        if (dohead) {
            const int th = p - 4;
            #pragma unroll
            for (int k = 0; k < 3; ++k) {
                const int a = w + 8*k;
                if (a < 19) {
                    float s = wpr[k].x*hh4.x + wpr[k].y*hh4.y + wpr[k].z*hh4.z + wpr[k].w*hh4.w;
                    s += __shfl_xor(s, 1);  s += __shfl_xor(s, 2);  s += __shfl_xor(s, 4);
                    s += __shfl_xor(s, 8);  s += __shfl_xor(s, 16); s += __shfl_xor(s, 32);
                    if (lane == 0) {
                        float v = s + wpb[k];
                        hlog[a] = v;
                        if (a < 18) out[((size_t)th*B_ + wl)*A_ + a] = v;
                        else        out[OUT_BASE + th*B_ + wl] = v;
                    }
                }
            }
        }

        // ---- staging + gate FMA ----
        const float4* s4 = (const float4*)stg;
        if (work) {
            const float nd = done[t*B_ + sb] ? 0.f : 1.f;
            ha.x *= nd; ha.y *= nd; ha.z *= nd; ha.w *= nd;
            hb.x *= nd; hb.y *= nd; hb.z *= nd; hb.w *= nd;

            // -- x-fragments into registers (forced: stg is clobbered after) --
            float4 xr4[4][4];
            if (l == 1) {
                ((float4*)stg)[tid*2]     = xa;
                ((float4*)stg)[tid*2 + 1] = xb;
                __syncthreads();
                #pragma unroll
                for (int jj = 0; jj < 4; ++jj)
                    #pragma unroll
                    for (int q = 0; q < 4; ++q)
                        xr4[jj][q] = s4[(jq*4 + jj)*64 + q*16 + kc];
                __syncthreads();                        // all x-reads done (WAR)
            } else {
                const float4* xb0 = (const float4*)(x + ((size_t)t*B_ + b0)*H_);
                #pragma unroll
                for (int jj = 0; jj < 4; ++jj)
                    #pragma unroll
                    for (int q = 0; q < 4; ++q)
                        xr4[jj][q] = xb0[(size_t)(jq*4 + jj)*64 + q*16 + kc];
            }

            // -- stage masked h (clobbers stg: x-frags now must live in regs) --
            ((float4*)stg)[tid*2]     = ha;
            ((float4*)stg)[tid*2 + 1] = hb;
            __syncthreads();

            // -- 2 batch-passes: 2 batches each; low live-set per pass --
            const float4* wl4 = (const float4*)wlds;
            #pragma unroll
            for (int pass = 0; pass < 2; ++pass) {
                const int j0 = pass*2;                   // batches jq*4+j0, +1
                float4 hr2[2][4];
                #pragma unroll
                for (int jp = 0; jp < 2; ++jp)
                    #pragma unroll
                    for (int q = 0; q < 4; ++q)
                        hr2[jp][q] = s4[(jq*4 + j0 + jp)*64 + q*16 + kc];
                #pragma unroll
                for (int rr = 0; rr < 8; ++rr) {
                    const int rs = w*8 + rr;
                    const int g  = rs >> 4, ri = rs & 15;
                    const int wb4 = rs*128;
                    float4 wiv[4], whv[4];
                    #pragma unroll
                    for (int q = 0; q < 4; ++q) {
                        wiv[q] = wl4[wb4 + q*16 + kc];
                        whv[q] = wl4[wb4 + 64 + q*16 + kc];
                    }
                    float accA = 0.f, accB = 0.f;
                    #pragma unroll
                    for (int q = 0; q < 4; ++q) {
                        accA += wiv[q].x*xr4[j0  ][q].x + wiv[q].y*xr4[j0  ][q].y
                              + wiv[q].z*xr4[j0  ][q].z + wiv[q].w*xr4[j0  ][q].w
                              + whv[q].x*hr2[0][q].x + whv[q].y*hr2[0][q].y
                              + whv[q].z*hr2[0][q].z + whv[q].w*hr2[0][q].w;
                        accB += wiv[q].x*xr4[j0+1][q].x + wiv[q].y*xr4[j0+1][q].y
                              + wiv[q].z*xr4[j0+1][q].z + wiv[q].w*xr4[j0+1][q].w
                              + whv[q].x*hr2[1][q].x + whv[q].y*hr2[1][q].y
                              + whv[q].z*hr2[1][q].z + whv[q].w*hr2[1][q].w;
                    }
                    accA = rowsum16(accA);
                    accB = rowsum16(accB);
                    const float v = (kc == j0) ? accA : accB;
                    if ((kc >> 1) == pass && kc < 4)     // kc in {2*pass, 2*pass+1}
                        gates[g][ri][jq*4 + kc] = v + bsum[rr];
                }
            }
        }

        __syncthreads();          // gates ready; also orders hlog for argmax

        // ---- cell update: tid<256, consecutive h -> 64B-coalesced swaps ----
        if (work && tid < 256) {
            const int j = tid >> 4, hi = tid & 15;
            const int b = b0 + j, h = hg*16 + hi;
            const float nd = done[t*B_ + b] ? 0.f : 1.f;
            if (t == 0) cr = c0in[(size_t)l*B_*H_ + b*H_ + h];
            const float cp = cr * nd;
            const float gi = gates[0][hi][j], gf = gates[1][hi][j];
            const float gv = gates[2][hi][j], go = gates[3][hi][j];
            const float ii = 1.f/(1.f + expf(-gi));
            const float ff = 1.f/(1.f + expf(-gf));
            const float gt = tanhf(gv);
            const float oo = 1.f/(1.f + expf(-go));
            const float cl = ff*cp + ii*gt;
            cr = cl;
            if (t == T_-1)
                cswap(ws + (l ? WS_C1 : WS_C0) + (size_t)b*H_ + h, cl);
            float* hout = ws + (l ? WS_H1 : WS_H0) + (size_t)(t&3)*B_*H_;
            cswap(hout + (size_t)b*H_ + h, oo*tanhf(cl));
        }

        // ---- argmax (hlog complete; ordered by the sync above) ----
        if (dohead && tid == 0) {
            const int th = p - 4;
            float best = hlog[0]; int bi = 0;
            #pragma unroll
            for (int a = 1; a < A_; ++a) { float v = hlog[a]; if (v > best) { best = v; bi = a; } }
            out[OUT_ACT + th*B_ + wl] = (float)bi;       // strict > = first-max, matches np
        }

        // ---- final state copy (L1, p=513: polls guarantee L0>=513, L1>=513) ----
        if (l == 1 && p == 513 && tid < 256) {
            const int idx = wl*H_ + tid;
            out[OUT_HT + idx]         = cload(ws + WS_H0 + 3*B_*H_ + idx);   // h0(511) slot 3
            out[OUT_HT + B_*H_ + idx] = cload(ws + WS_H1 + 3*B_*H_ + idx);   // h1(511) slot 3
            out[OUT_CT + idx]         = cload(ws + WS_C0 + idx);
            out[OUT_CT + B_*H_ + idx] = cload(ws + WS_C1 + idx);
        }

        // ---- decoupled cluster barrier ----
        if (p < 515) {
            asm volatile("s_waitcnt vmcnt(0)" ::: "memory");   // swaps acked at L3
            __syncthreads();
            if (tid == 0)
                __hip_atomic_store(stamp + wg, (unsigned)(p + 1),
                                   __ATOMIC_RELAXED, __HIP_MEMORY_SCOPE_SYSTEM);
            if (tid < 32) {
                const bool own = (tid < 16);
                const int  i   = tid & 15;
                const int  cell = (own ? l : (1 - l))*128 + bt*16 + i;
                // L0: own >= p+1, L1 (other) >= p-1 (lag-2). L1: both >= p+1.
                const int tgt = own ? (p + 1) : ((l == 0) ? (p - 1) : (p + 1));
                if (tgt > 0)
                    while (__hip_atomic_load(stamp + cell, __ATOMIC_RELAXED,
                                             __HIP_MEMORY_SCOPE_SYSTEM) < (unsigned)tgt)
                        __builtin_amdgcn_s_sleep(1);
            }
            __syncthreads();
        }
    }
}

extern "C" void kernel_launch(void* const* d_in, const int* in_sizes, int n_in,
                              void* d_out, int out_size, void* d_ws, size_t ws_size,
                              hipStream_t stream)
{
    const float* x    = (const float*)d_in[0];
    const int*   done = (const int*)  d_in[1];
    const float* h0   = (const float*)d_in[2];
    const float* c0   = (const float*)d_in[3];
    const float* w_ih = (const float*)d_in[4];
    const float* w_hh = (const float*)d_in[5];
    const float* b_ih = (const float*)d_in[6];
    const float* b_hh = (const float*)d_in[7];
    const float* Wp   = (const float*)d_in[8];
    const float* bp   = (const float*)d_in[9];
    const float* Wb   = (const float*)d_in[10];
    const float* bb   = (const float*)d_in[11];
    float* out = (float*)d_out;
    float* ws  = (float*)d_ws;    // 1.31 MB state + 1 KB stamp cells

    // zero the 256 stamp cells (captured node, re-runs every replay)
    hipMemsetAsync((char*)d_ws + (size_t)WS_CTR*sizeof(float), 0, 1024, stream);

    lstm_persist<<<dim3(256), dim3(512), 0, stream>>>(
        x, done, h0, c0, w_ih, w_hh, b_ih, b_hh, Wp, bp, Wb, bb, out, ws);
}